// Round 1
// baseline (1825.995 us; speedup 1.0000x reference)
//
#include <hip/hip_runtime.h>
#include <math.h>

#define NN 50000
#define NE 800000
#define IND 256
#define HD 128
#define NH 4
#define NC 32
#define RELN 100
#define RD 16
#define EHD 32

// ---------------- edge feature MLPs + degree count ----------------
__global__ __launch_bounds__(256) void edge_feat_kernel(
    const float* __restrict__ eattr, const int* __restrict__ dst,
    const float* __restrict__ dW1, const float* __restrict__ db1,
    const float* __restrict__ dW2, const float* __restrict__ db2,
    const float* __restrict__ cW1, const float* __restrict__ cb1,
    const float* __restrict__ cW2, const float* __restrict__ cb2,
    const float* __restrict__ rel_emb,
    const float* __restrict__ fW1, const float* __restrict__ fb1,
    const float* __restrict__ fg,  const float* __restrict__ fbl,
    const float* __restrict__ fW2, const float* __restrict__ fb2,
    float* __restrict__ efeat, int* __restrict__ counts)
{
    int e = blockIdx.x * 256 + threadIdx.x;
    if (e >= NE) return;
    float d  = eattr[(size_t)e * 3 + 0];
    float cx = eattr[(size_t)e * 3 + 1];
    int r = (int)eattr[(size_t)e * 3 + 2];
    r = min(max(r, 0), RELN - 1);

    float df[RD], cf[RD];
#pragma unroll
    for (int k = 0; k < RD; k++) { df[k] = db2[k]; cf[k] = cb2[k]; }
    for (int j = 0; j < EHD; j++) {
        float h1 = fmaxf(d  * dW1[j] + db1[j], 0.f);
        float h2 = fmaxf(cx * cW1[j] + cb1[j], 0.f);
#pragma unroll
        for (int k = 0; k < RD; k++) {
            df[k] += h1 * dW2[j * RD + k];
            cf[k] += h2 * cW2[j * RD + k];
        }
    }
    float hh[2 * RD];
#pragma unroll
    for (int m = 0; m < 2 * RD; m++) hh[m] = fb1[m];
    for (int k = 0; k < RD; k++) {
        float a = df[k], b = cf[k], c = rel_emb[r * RD + k];
#pragma unroll
        for (int m = 0; m < 2 * RD; m++) {
            hh[m] += a * fW1[k * (2 * RD) + m]
                   + b * fW1[(RD + k) * (2 * RD) + m]
                   + c * fW1[(2 * RD + k) * (2 * RD) + m];
        }
    }
    // LN over 32 then relu
    float s = 0.f;
#pragma unroll
    for (int m = 0; m < 2 * RD; m++) s += hh[m];
    float mean = s * (1.f / (2 * RD));
    float s2 = 0.f;
#pragma unroll
    for (int m = 0; m < 2 * RD; m++) { float dd = hh[m] - mean; s2 += dd * dd; }
    float rs = rsqrtf(s2 * (1.f / (2 * RD)) + 1e-5f);
#pragma unroll
    for (int m = 0; m < 2 * RD; m++)
        hh[m] = fmaxf((hh[m] - mean) * rs * fg[m] + fbl[m], 0.f);

    float ef[RD];
#pragma unroll
    for (int k = 0; k < RD; k++) ef[k] = fb2[k];
    for (int m = 0; m < 2 * RD; m++) {
        float hv = hh[m];
#pragma unroll
        for (int k = 0; k < RD; k++) ef[k] += hv * fW2[m * RD + k];
    }
#pragma unroll
    for (int k = 0; k < RD; k++) efeat[(size_t)e * RD + k] = ef[k];

    atomicAdd(&counts[dst[e]], 1);
}

// ---------------- exclusive scan (single block) ----------------
__global__ __launch_bounds__(1024) void scan_kernel(
    const int* __restrict__ counts, int* __restrict__ row_ptr,
    int* __restrict__ cursor, int n)
{
    __shared__ int buf[1024];
    __shared__ int carry_s;
    int tid = threadIdx.x;
    if (tid == 0) carry_s = 0;
    __syncthreads();
    for (int base = 0; base < n; base += 1024) {
        int i = base + tid;
        int v = (i < n) ? counts[i] : 0;
        buf[tid] = v;
        __syncthreads();
        for (int off = 1; off < 1024; off <<= 1) {
            int t = (tid >= off) ? buf[tid - off] : 0;
            __syncthreads();
            buf[tid] += t;
            __syncthreads();
        }
        int incl = buf[tid];
        int c = carry_s;
        if (i < n) { row_ptr[i] = c + incl - v; cursor[i] = c + incl - v; }
        __syncthreads();
        if (tid == 0) carry_s = c + buf[1023];
        __syncthreads();
    }
    if (tid == 0) row_ptr[n] = carry_s;
}

// ---------------- CSR fill ----------------
__global__ __launch_bounds__(256) void fill_kernel(
    const int* __restrict__ dst, int* __restrict__ cursor, int* __restrict__ eids)
{
    int e = blockIdx.x * 256 + threadIdx.x;
    if (e < NE) {
        int p = atomicAdd(&cursor[dst[e]], 1);
        eids[p] = e;
    }
}

// ---------------- input LN + projection (8 nodes / block) ----------------
__global__ __launch_bounds__(256) void ln_proj_kernel(
    const float* __restrict__ x, const float* __restrict__ g, const float* __restrict__ b,
    const float* __restrict__ W, const float* __restrict__ pb, float* __restrict__ x0)
{
    __shared__ float xr[8][IND];
    __shared__ float mv[8][2];
    int nb = blockIdx.x * 8;
    int tid = threadIdx.x;
    const float4* xv = (const float4*)(x + (size_t)nb * IND);
    float4* xl = (float4*)&xr[0][0];
    xl[tid] = xv[tid];
    xl[tid + 256] = xv[tid + 256];
    __syncthreads();
    int node = tid >> 5, lane = tid & 31;
    float s1 = 0.f, s2 = 0.f;
#pragma unroll
    for (int j = 0; j < 8; j++) { float v = xr[node][lane + 32 * j]; s1 += v; s2 += v * v; }
#pragma unroll
    for (int off = 16; off >= 1; off >>= 1) { s1 += __shfl_xor(s1, off); s2 += __shfl_xor(s2, off); }
    if (lane == 0) {
        float mean = s1 * (1.f / IND);
        mv[node][0] = mean;
        mv[node][1] = rsqrtf(s2 * (1.f / IND) - mean * mean + 1e-5f);
    }
    __syncthreads();
#pragma unroll
    for (int j = 0; j < 8; j++) {
        int k = lane + 32 * j;
        xr[node][k] = (xr[node][k] - mv[node][0]) * mv[node][1] * g[k] + b[k];
    }
    __syncthreads();
    int col = tid & 127, r0 = (tid >> 7) * 4;
    float acc[4] = {0.f, 0.f, 0.f, 0.f};
    for (int k = 0; k < IND; k++) {
        float w = W[k * HD + col];
#pragma unroll
        for (int r = 0; r < 4; r++) acc[r] += xr[r0 + r][k] * w;
    }
    float pbv = pb[col];
#pragma unroll
    for (int r = 0; r < 4; r++)
        x0[(size_t)(nb + r0 + r) * HD + col] = acc[r] + pbv;
}

// ---------------- xs/xd = x @ [Wsrc | Wdst] ----------------
__global__ __launch_bounds__(256) void gemm_sd_kernel(
    const float* __restrict__ x, const float* __restrict__ Ws, const float* __restrict__ Wd,
    float* __restrict__ xs, float* __restrict__ xd)
{
    __shared__ float xt[32][HD];
    int nb = blockIdx.x * 32;
    int tid = threadIdx.x;
    const float4* xv = (const float4*)(x + (size_t)nb * HD);
    float4* xl = (float4*)&xt[0][0];
    int validf4 = (NN - nb >= 32) ? 1024 : (NN - nb) * 32;
    for (int idx = tid; idx < 1024; idx += 256) {
        float4 v = {0.f, 0.f, 0.f, 0.f};
        if (idx < validf4) v = xv[idx];
        xl[idx] = v;
    }
    __syncthreads();
    int ct = blockIdx.y;
    const float* W = (ct < 2) ? Ws : Wd;
    float* out = (ct < 2) ? xs : xd;
    int col = (ct & 1) * 64 + (tid & 63);
    int r0 = (tid >> 6) * 8;
    float acc[8] = {0.f};
    for (int k = 0; k < HD; k++) {
        float w = W[k * HD + col];
#pragma unroll
        for (int r = 0; r < 8; r++) acc[r] += xt[r0 + r][k] * w;
    }
#pragma unroll
    for (int r = 0; r < 8; r++) {
        int n = nb + r0 + r;
        if (n < NN) out[(size_t)n * HD + col] = acc[r];
    }
}

// ---------------- per-layer attention aggregate + LN + ELU + residual ----------------
__global__ __launch_bounds__(128) void aggregate_kernel(
    const float* __restrict__ xs, const float* __restrict__ xd,
    const float* __restrict__ efeat, const float* __restrict__ eattr,
    const int* __restrict__ src, const int* __restrict__ row_ptr,
    const int* __restrict__ eids,
    const float* __restrict__ Wedge_i, const float* __restrict__ att_i,
    const float* __restrict__ sscale_i, const float* __restrict__ ng_i,
    const float* __restrict__ nb_i, float* __restrict__ xio, int apply_dist)
{
    __shared__ float wedge_s[RD * HD];
    __shared__ float rs1[2], rs2[2];
    int node = blockIdx.x;
    int t = threadIdx.x;
    for (int idx = t; idx < RD * HD; idx += 128) wedge_s[idx] = Wedge_i[idx];
    int h = t >> 5;
    float attv = att_i[t];
    float xdv = xd[(size_t)node * HD + t];
    float xres = xio[(size_t)node * HD + t];
    float sc = sscale_i[h];
    __syncthreads();

    float esum = 0.f, macc = 0.f;
    int e0 = row_ptr[node], e1 = row_ptr[node + 1];
    for (int ei = e0; ei < e1; ei++) {
        int e = eids[ei];
        int s = src[e];
        float xsv = xs[(size_t)s * HD + t];
        const float* efp = &efeat[(size_t)e * RD];
        float ef = 0.f;
#pragma unroll
        for (int k = 0; k < RD; k++) ef += efp[k] * wedge_s[k * HD + t];
        float a = tanhf(xsv + xdv + ef) * attv;
#pragma unroll
        for (int off = 16; off >= 1; off >>= 1) a += __shfl_xor(a, off);
        if (apply_dist) {
            float dw = eattr[(size_t)e * 3];
            a *= __powf(dw, sc);
        }
        float ea = __expf(a);
        esum += ea;
        macc += xsv * ea;
    }
    float outv = macc / (esum + 1e-8f);

    // LN over 128
    float s1 = outv, s2 = outv * outv;
#pragma unroll
    for (int off = 32; off >= 1; off >>= 1) { s1 += __shfl_xor(s1, off); s2 += __shfl_xor(s2, off); }
    if ((t & 63) == 0) { rs1[t >> 6] = s1; rs2[t >> 6] = s2; }
    __syncthreads();
    float S1 = rs1[0] + rs1[1], S2 = rs2[0] + rs2[1];
    float mean = S1 * (1.f / HD);
    float var = S2 * (1.f / HD) - mean * mean;
    float y = (outv - mean) * rsqrtf(var + 1e-5f) * ng_i[t] + nb_i[t];
    float el = (y > 0.f) ? y : expm1f(y);
    xio[(size_t)node * HD + t] = el + xres;
}

extern "C" void kernel_launch(void* const* d_in, const int* in_sizes, int n_in,
                              void* d_out, int out_size, void* d_ws, size_t ws_size,
                              hipStream_t stream)
{
    const float* x_in   = (const float*)d_in[0];
    const int*   eidx   = (const int*)  d_in[1];
    const float* eattr  = (const float*)d_in[2];
    const float* in_g   = (const float*)d_in[3];
    const float* in_b   = (const float*)d_in[4];
    const float* proj_W = (const float*)d_in[5];
    const float* proj_b = (const float*)d_in[6];
    const float* dW1    = (const float*)d_in[7];
    const float* db1    = (const float*)d_in[8];
    const float* dW2    = (const float*)d_in[9];
    const float* db2    = (const float*)d_in[10];
    const float* cW1    = (const float*)d_in[11];
    const float* cb1    = (const float*)d_in[12];
    const float* cW2    = (const float*)d_in[13];
    const float* cb2    = (const float*)d_in[14];
    const float* rel_emb= (const float*)d_in[15];
    const float* fW1    = (const float*)d_in[16];
    const float* fb1    = (const float*)d_in[17];
    const float* fg     = (const float*)d_in[18];
    const float* fbl    = (const float*)d_in[19];
    const float* fW2    = (const float*)d_in[20];
    const float* fb2    = (const float*)d_in[21];
    const float* Wsrc   = (const float*)d_in[22];
    const float* Wdst   = (const float*)d_in[23];
    const float* Wedge  = (const float*)d_in[24];
    const float* att    = (const float*)d_in[25];
    const float* sscale = (const float*)d_in[26];
    const float* ng     = (const float*)d_in[27];
    const float* nb     = (const float*)d_in[28];

    const int* src = eidx;
    const int* dst = eidx + NE;

    char* p = (char*)d_ws;
    auto alloc = [&](size_t bytes) -> void* {
        void* r = p;
        p += (bytes + 255) & ~(size_t)255;
        return r;
    };
    float* xs     = (float*)alloc((size_t)NN * HD * 4);
    float* xd     = (float*)alloc((size_t)NN * HD * 4);
    float* efeat  = (float*)alloc((size_t)NE * RD * 4);
    int*   counts = (int*)  alloc((size_t)NN * 4);
    int*   row_ptr= (int*)  alloc(((size_t)NN + 1) * 4);
    int*   cursor = (int*)  alloc((size_t)NN * 4);
    int*   eids   = (int*)  alloc((size_t)NE * 4);

    float* x_cur = (float*)d_out;

    hipMemsetAsync(counts, 0, (size_t)NN * 4, stream);
    hipLaunchKernelGGL(edge_feat_kernel, dim3(NE / 256), dim3(256), 0, stream,
        eattr, dst, dW1, db1, dW2, db2, cW1, cb1, cW2, cb2, rel_emb,
        fW1, fb1, fg, fbl, fW2, fb2, efeat, counts);
    hipLaunchKernelGGL(scan_kernel, dim3(1), dim3(1024), 0, stream,
        counts, row_ptr, cursor, NN);
    hipLaunchKernelGGL(fill_kernel, dim3(NE / 256), dim3(256), 0, stream,
        dst, cursor, eids);
    hipLaunchKernelGGL(ln_proj_kernel, dim3(NN / 8), dim3(256), 0, stream,
        x_in, in_g, in_b, proj_W, proj_b, x_cur);

    for (int i = 0; i < 3; i++) {
        hipLaunchKernelGGL(gemm_sd_kernel, dim3((NN + 31) / 32, 4), dim3(256), 0, stream,
            x_cur, Wsrc + (size_t)i * HD * HD, Wdst + (size_t)i * HD * HD, xs, xd);
        hipLaunchKernelGGL(aggregate_kernel, dim3(NN), dim3(128), 0, stream,
            xs, xd, efeat, eattr, src, row_ptr, eids,
            Wedge + (size_t)i * RD * HD, att + (size_t)i * NH * NC,
            sscale + (size_t)i * NH, ng + (size_t)i * HD, nb + (size_t)i * HD,
            x_cur, (i < 2) ? 1 : 0);
    }
}